// Round 5
// baseline (398.827 us; speedup 1.0000x reference)
//
#include <hip/hip_runtime.h>

// Problem constants
constexpr int N  = 50000;    // nodes
constexpr int E  = 1600000;  // edges
constexpr int CH = 128;      // channels

// Bucketed CSR build parameters
constexpr int BSZ  = 128;                  // nodes per bucket
constexpr int NB   = (N + BSZ - 1) / BSZ;  // 391 buckets
constexpr int PBLK = 256;                  // partition blocks
constexpr int EPB  = E / PBLK;             // 6250 edges per partition block
constexpr int TOT  = NB * PBLK;            // 100096 (bucket,block) counters

// Workspace layout (bytes, 256-aligned)
constexpr size_t H_OFF    = 0;                        // h bf16 [N*CH]
constexpr size_t H_SZ     = (size_t)N * CH * 2;       // 12,800,000
constexpr size_t WBF_OFF  = H_OFF + H_SZ;             // W bf16 [CH*CH]
constexpr size_t WBF_SZ   = (size_t)CH * CH * 2;      // 32,768
constexpr size_t DSTS_OFF = WBF_OFF + WBF_SZ;         // bucket-sorted dst [E]
constexpr size_t SRCS_OFF = DSTS_OFF + (size_t)E * 4; // bucket-sorted src [E]
constexpr size_t CSR_OFF  = SRCS_OFF + (size_t)E * 4; // csr src ids [E]
constexpr size_t CNT_OFF  = CSR_OFF + (size_t)E * 4;  // counts [NB][PBLK]
constexpr size_t CNT_SZ   = (size_t)TOT * 4;          // 400,384
constexpr size_t DEG_OFF  = CNT_OFF + CNT_SZ;         // degree [N]
constexpr size_t DEG_SZ   = 200704;
constexpr size_t OFFS_OFF = DEG_OFF + DEG_SZ;         // offsets [N]
constexpr size_t OFFS_SZ  = 200704;
constexpr size_t BASE_OFF = OFFS_OFF + OFFS_SZ;       // bucket bases [NB+1]
constexpr size_t BASE_SZ  = 2048;
constexpr size_t REQUIRED = BASE_OFF + BASE_SZ;       // ~32.8 MB
constexpr size_t FB_REQUIRED = DSTS_OFF;              // fallback: h + wbf only

// float -> bf16 round-to-nearest-even (finite inputs)
static __device__ __forceinline__ ushort f2bf(float f) {
    unsigned u = __float_as_uint(f);
    return (ushort)((u + 0x7fffu + ((u >> 16) & 1u)) >> 16);
}
static __device__ __forceinline__ float bf_lo(unsigned u) { return __uint_as_float(u << 16); }
static __device__ __forceinline__ float bf_hi(unsigned u) { return __uint_as_float(u & 0xffff0000u); }

typedef __attribute__((ext_vector_type(8))) short bf16x8;
typedef __attribute__((ext_vector_type(4))) float f32x4;

// ---------------- W fp32 -> bf16 (fallback path only) ----------------
__global__ void convert_w(const float* __restrict__ W, ushort* __restrict__ wbf) {
    int i = blockIdx.x * 256 + threadIdx.x;
    wbf[i] = f2bf(W[i]);
}

// ---------------- GEMM via MFMA: h = bf16(x @ W^T + b) ----------------
// Block = 4 waves, 16 rows x 128 cols. Verified layouts (m89/m91):
// A[m=lane&15][k=q*8+j], B[n=lane&15][k=q*8+j], D col=lane&15,row=q*4+reg.
__global__ __launch_bounds__(256) void gemm_mfma(const float* __restrict__ x,
                                                 const ushort* __restrict__ wbf,
                                                 const float* __restrict__ bias,
                                                 ushort* __restrict__ h) {
    const int tid  = threadIdx.x;
    const int m    = tid & 15;
    const int q    = (tid >> 4) & 3;
    const int wave = tid >> 6;
    const int r0   = blockIdx.x * 16;
    const int c0   = wave * 32;

    const float*  xrow = x + (size_t)(r0 + m) * CH + q * 8;
    const ushort* w0   = wbf + (size_t)(c0 + m) * CH + q * 8;
    const ushort* w1   = w0 + 16 * CH;

    f32x4 acc0 = {0.f, 0.f, 0.f, 0.f};
    f32x4 acc1 = {0.f, 0.f, 0.f, 0.f};

#pragma unroll
    for (int kc = 0; kc < CH; kc += 32) {
        float4 xa = *(const float4*)(xrow + kc);
        float4 xb = *(const float4*)(xrow + kc + 4);
        bf16x8 a;
        a[0] = (short)f2bf(xa.x); a[1] = (short)f2bf(xa.y);
        a[2] = (short)f2bf(xa.z); a[3] = (short)f2bf(xa.w);
        a[4] = (short)f2bf(xb.x); a[5] = (short)f2bf(xb.y);
        a[6] = (short)f2bf(xb.z); a[7] = (short)f2bf(xb.w);
        bf16x8 b0 = *(const bf16x8*)(w0 + kc);
        bf16x8 b1 = *(const bf16x8*)(w1 + kc);
        acc0 = __builtin_amdgcn_mfma_f32_16x16x32_bf16(a, b0, acc0, 0, 0, 0);
        acc1 = __builtin_amdgcn_mfma_f32_16x16x32_bf16(a, b1, acc1, 0, 0, 0);
    }

    const int col0 = c0 + m;
    const float bb0 = bias[col0];
    const float bb1 = bias[col0 + 16];
#pragma unroll
    for (int r = 0; r < 4; r++) {
        size_t row = (size_t)(r0 + q * 4 + r) * CH;
        h[row + col0]      = f2bf(acc0[r] + bb0);
        h[row + col0 + 16] = f2bf(acc1[r] + bb1);
    }
}

// ---------------- pass 1a: per-block bucket histogram (+ fused W convert) ----------------
__global__ __launch_bounds__(256) void p1_count(const int* __restrict__ ei,
                                                int* __restrict__ counts,
                                                const float* __restrict__ W,
                                                ushort* __restrict__ wbf) {
    __shared__ int cnt[NB];
    const int t = threadIdx.x, k = blockIdx.x;
    if (k >= PBLK) {                 // 64 extra blocks: convert W to bf16
        int i = (k - PBLK) * 256 + t;
        wbf[i] = f2bf(W[i]);
        return;
    }
    for (int j = t; j < NB; j += 256) cnt[j] = 0;
    __syncthreads();
    const int* dp = ei + k * EPB;
    for (int i = t; i < EPB; i += 256) atomicAdd(&cnt[dp[i] >> 7], 1);
    __syncthreads();
    for (int j = t; j < NB; j += 256) counts[j * PBLK + k] = cnt[j];  // bucket-major
}

// ---------------- scan of TOT (bucket,block) counts, in place ----------------
__global__ __launch_bounds__(1024) void scan_counts(int* __restrict__ counts,
                                                    int* __restrict__ base) {
    __shared__ int s[1024];
    const int t = threadIdx.x;
    const int PER = (TOT + 1023) / 1024;    // 98
    const int b0 = t * PER;
    int sum = 0;
    for (int i = 0; i < PER; i++) {
        int j = b0 + i;
        if (j < TOT) sum += counts[j];
    }
    s[t] = sum;
    __syncthreads();
    for (int o = 1; o < 1024; o <<= 1) {
        int v = (t >= o) ? s[t - o] : 0;
        __syncthreads();
        s[t] += v;
        __syncthreads();
    }
    int run = s[t] - sum;
    for (int i = 0; i < PER; i++) {
        int j = b0 + i;
        if (j < TOT) { int v = counts[j]; counts[j] = run; run += v; }
    }
    __syncthreads();
    if (t < NB)  base[t]  = counts[t * PBLK];
    if (t == 0)  base[NB] = E;
}

// ---------------- pass 1b: scatter (dst,src) into private per-(bucket,block) slots, SoA ----------------
__global__ __launch_bounds__(256) void p1_write(const int* __restrict__ ei,
                                                const int* __restrict__ counts,
                                                int* __restrict__ dsts,
                                                int* __restrict__ srcs) {
    __shared__ int cur[NB];
    const int t = threadIdx.x, k = blockIdx.x;
    for (int j = t; j < NB; j += 256) cur[j] = counts[j * PBLK + k];
    __syncthreads();
    const int* dp = ei + k * EPB;
    const int* sp = ei + E + k * EPB;
    for (int i = t; i < EPB; i += 256) {
        int d = dp[i], s = sp[i];
        int p = atomicAdd(&cur[d >> 7], 1);
        dsts[p] = d;
        srcs[p] = s;
    }
}

// ---------------- pass 2: per-bucket local CSR build ----------------
__global__ __launch_bounds__(256) void p2_build(const int* __restrict__ dsts,
                                                const int* __restrict__ srcs,
                                                const int* __restrict__ base,
                                                int* __restrict__ deg,
                                                int* __restrict__ offs,
                                                int* __restrict__ csr) {
    __shared__ int hist[BSZ], scn[BSZ], cur[BSZ];
    const int b = blockIdx.x, t = threadIdx.x;
    const int lo = base[b], cnt = base[b + 1] - lo;
    if (t < BSZ) hist[t] = 0;
    __syncthreads();
    for (int i = t; i < cnt; i += 256) atomicAdd(&hist[dsts[lo + i] & (BSZ - 1)], 1);
    __syncthreads();
    if (t < BSZ) scn[t] = hist[t];
    __syncthreads();
    for (int o = 1; o < BSZ; o <<= 1) {
        int v = 0;
        if (t < BSZ && t >= o) v = scn[t - o];
        __syncthreads();
        if (t < BSZ) scn[t] += v;
        __syncthreads();
    }
    if (t < BSZ) {
        int excl = scn[t] - hist[t];
        cur[t] = excl;
        int n = b * BSZ + t;
        if (n < N) { deg[n] = hist[t]; offs[n] = lo + excl; }
    }
    __syncthreads();
    for (int i = t; i < cnt; i += 256) {
        int d = dsts[lo + i], s = srcs[lo + i];
        int p = atomicAdd(&cur[d & (BSZ - 1)], 1);
        csr[lo + p] = s;
    }
}

// ---------------- pull aggregation, high-MLP ----------------
// 4 waves/block, one node per wave. Within a wave: half-waves process
// different edges; lane reads 8 B (4 bf16) -> one 256 B row per half-wave.
// Unroll x4 => 8 rows in flight per wave. Cross-half shfl_xor reduce.
__global__ __launch_bounds__(256) void agg_bf16(const ushort* __restrict__ h,
                                                const int* __restrict__ offs,
                                                const int* __restrict__ deg,
                                                const int* __restrict__ csr,
                                                float* __restrict__ out) {
    const int lane = threadIdx.x & 63;
    const int half = lane >> 5;          // 0/1
    const int cl   = lane & 31;          // channel quad 0..31
    const int n    = blockIdx.x * 4 + (threadIdx.x >> 6);
    const int st   = offs[n];
    const int cnt  = deg[n];
    const ushort* hp = h + (size_t)cl * 4;

    float a0 = 0.f, a1 = 0.f, a2 = 0.f, a3 = 0.f;
    int i = 0;
    for (; i + 8 <= cnt; i += 8) {
        const int e0 = st + i + half;
        int s0 = csr[e0];
        int s1 = csr[e0 + 2];
        int s2 = csr[e0 + 4];
        int s3 = csr[e0 + 6];
        uint2 v0 = *(const uint2*)(hp + (size_t)s0 * CH);
        uint2 v1 = *(const uint2*)(hp + (size_t)s1 * CH);
        uint2 v2 = *(const uint2*)(hp + (size_t)s2 * CH);
        uint2 v3 = *(const uint2*)(hp + (size_t)s3 * CH);
        a0 += bf_lo(v0.x); a1 += bf_hi(v0.x); a2 += bf_lo(v0.y); a3 += bf_hi(v0.y);
        a0 += bf_lo(v1.x); a1 += bf_hi(v1.x); a2 += bf_lo(v1.y); a3 += bf_hi(v1.y);
        a0 += bf_lo(v2.x); a1 += bf_hi(v2.x); a2 += bf_lo(v2.y); a3 += bf_hi(v2.y);
        a0 += bf_lo(v3.x); a1 += bf_hi(v3.x); a2 += bf_lo(v3.y); a3 += bf_hi(v3.y);
    }
    for (; i + 2 <= cnt; i += 2) {
        int s = csr[st + i + half];
        uint2 v = *(const uint2*)(hp + (size_t)s * CH);
        a0 += bf_lo(v.x); a1 += bf_hi(v.x); a2 += bf_lo(v.y); a3 += bf_hi(v.y);
    }
    if (i + half < cnt) {                // odd tail: half 0 only
        int s = csr[st + i + half];
        uint2 v = *(const uint2*)(hp + (size_t)s * CH);
        a0 += bf_lo(v.x); a1 += bf_hi(v.x); a2 += bf_lo(v.y); a3 += bf_hi(v.y);
    }
    // combine the two half-waves
    a0 += __shfl_xor(a0, 32);
    a1 += __shfl_xor(a1, 32);
    a2 += __shfl_xor(a2, 32);
    a3 += __shfl_xor(a3, 32);
    if (half == 0) {
        float4 r = make_float4(a0, a1, a2, a3);
        *(float4*)(out + (size_t)n * CH + cl * 4) = r;
    }
}

// ---------------- fallback: direct atomic scatter ----------------
__global__ void atomic_agg(const ushort* __restrict__ h, const int* __restrict__ ei,
                           float* __restrict__ out) {
    int tid = blockIdx.x * blockDim.x + threadIdx.x;
    int e  = tid >> 5;
    int cg = (tid & 31) * 4;
    if (e < E) {
        int d = ei[e];
        int s = ei[E + e];
        ushort4 v = *(const ushort4*)(h + (size_t)s * CH + cg);
        float* o = out + (size_t)d * CH + cg;
        atomicAdd(o + 0, __uint_as_float((unsigned)v.x << 16));
        atomicAdd(o + 1, __uint_as_float((unsigned)v.y << 16));
        atomicAdd(o + 2, __uint_as_float((unsigned)v.z << 16));
        atomicAdd(o + 3, __uint_as_float((unsigned)v.w << 16));
    }
}

extern "C" void kernel_launch(void* const* d_in, const int* in_sizes, int n_in,
                              void* d_out, int out_size, void* d_ws, size_t ws_size,
                              hipStream_t stream) {
    const float* x  = (const float*)d_in[0];
    const int*   ei = (const int*)d_in[1];   // [2][E] int32: row0=dst, row1=src
    const float* W  = (const float*)d_in[2];
    const float* b  = (const float*)d_in[3];
    float* out = (float*)d_out;

    char* ws = (char*)d_ws;
    ushort* h   = (ushort*)(ws + H_OFF);
    ushort* wbf = (ushort*)(ws + WBF_OFF);

    if (ws_size >= REQUIRED) {
        int* dsts   = (int*)(ws + DSTS_OFF);
        int* srcs   = (int*)(ws + SRCS_OFF);
        int* csr    = (int*)(ws + CSR_OFF);
        int* counts = (int*)(ws + CNT_OFF);
        int* deg    = (int*)(ws + DEG_OFF);
        int* offs   = (int*)(ws + OFFS_OFF);
        int* base   = (int*)(ws + BASE_OFF);

        p1_count<<<PBLK + 64, 256, 0, stream>>>(ei, counts, W, wbf);  // + W convert
        gemm_mfma<<<N / 16, 256, 0, stream>>>(x, wbf, b, h);
        scan_counts<<<1, 1024, 0, stream>>>(counts, base);
        p1_write<<<PBLK, 256, 0, stream>>>(ei, counts, dsts, srcs);
        p2_build<<<NB, 256, 0, stream>>>(dsts, srcs, base, deg, offs, csr);
        agg_bf16<<<N / 4, 256, 0, stream>>>(h, offs, deg, csr, out);
    } else if (ws_size >= FB_REQUIRED) {
        convert_w<<<64, 256, 0, stream>>>(W, wbf);
        gemm_mfma<<<N / 16, 256, 0, stream>>>(x, wbf, b, h);
        hipMemsetAsync(out, 0, (size_t)out_size * sizeof(float), stream);
        int total = E * 32;
        atomic_agg<<<(total + 255) / 256, 256, 0, stream>>>(h, ei, out);
    }
}

// Round 6
// 222.295 us; speedup vs baseline: 1.7941x; 1.7941x over previous
//
#include <hip/hip_runtime.h>

// Problem constants
constexpr int N  = 50000;    // nodes
constexpr int E  = 1600000;  // edges
constexpr int CH = 128;      // channels

// Bucketed CSR build parameters
constexpr int BSZ  = 128;                  // nodes per bucket
constexpr int NB   = (N + BSZ - 1) / BSZ;  // 391 buckets
constexpr int PBLK = 256;                  // partition blocks
constexpr int EPB  = E / PBLK;             // 6250 edges per partition block

// Workspace layout (bytes, 256-aligned)
constexpr size_t H_OFF    = 0;                        // h bf16 [N*CH]
constexpr size_t H_SZ     = (size_t)N * CH * 2;       // 12,800,000
constexpr size_t WBF_OFF  = H_OFF + H_SZ;             // W bf16 [CH*CH]
constexpr size_t WBF_SZ   = (size_t)CH * CH * 2;      // 32,768
constexpr size_t DSTS_OFF = WBF_OFF + WBF_SZ;         // bucket-sorted dst [E]
constexpr size_t SRCS_OFF = DSTS_OFF + (size_t)E * 4; // bucket-sorted src [E]
constexpr size_t CSR_OFF  = SRCS_OFF + (size_t)E * 4; // csr src ids [E]
constexpr size_t CNT_OFF  = CSR_OFF + (size_t)E * 4;  // counts [NB][PBLK]
constexpr size_t CNT_SZ   = (size_t)NB * PBLK * 4;    // 400,384
constexpr size_t DEG_OFF  = CNT_OFF + CNT_SZ;         // degree [N]
constexpr size_t DEG_SZ   = 200704;
constexpr size_t OFFS_OFF = DEG_OFF + DEG_SZ;         // offsets [N]
constexpr size_t OFFS_SZ  = 200704;
constexpr size_t BASE_OFF = OFFS_OFF + OFFS_SZ;       // bucket bases [NB+1]
constexpr size_t BASE_SZ  = 2048;
constexpr size_t BTOT_OFF = BASE_OFF + BASE_SZ;       // bucket totals [NB]
constexpr size_t BTOT_SZ  = 2048;
constexpr size_t REQUIRED = BTOT_OFF + BTOT_SZ;       // ~32.8 MB
constexpr size_t FB_REQUIRED = DSTS_OFF;              // fallback: h + wbf only

// float -> bf16 round-to-nearest-even (finite inputs)
static __device__ __forceinline__ ushort f2bf(float f) {
    unsigned u = __float_as_uint(f);
    return (ushort)((u + 0x7fffu + ((u >> 16) & 1u)) >> 16);
}
static __device__ __forceinline__ float bf_lo(unsigned u) { return __uint_as_float(u << 16); }
static __device__ __forceinline__ float bf_hi(unsigned u) { return __uint_as_float(u & 0xffff0000u); }

typedef __attribute__((ext_vector_type(8))) short bf16x8;
typedef __attribute__((ext_vector_type(4))) float f32x4;

// ---------------- W fp32 -> bf16 (fallback path only) ----------------
__global__ void convert_w(const float* __restrict__ W, ushort* __restrict__ wbf) {
    int i = blockIdx.x * 256 + threadIdx.x;
    wbf[i] = f2bf(W[i]);
}

// ---------------- GEMM via MFMA: h = bf16(x @ W^T + b) ----------------
// Block = 4 waves, 16 rows x 128 cols. Verified layouts (m89/m91):
// A[m=lane&15][k=q*8+j], B[n=lane&15][k=q*8+j], D col=lane&15,row=q*4+reg.
__global__ __launch_bounds__(256) void gemm_mfma(const float* __restrict__ x,
                                                 const ushort* __restrict__ wbf,
                                                 const float* __restrict__ bias,
                                                 ushort* __restrict__ h) {
    const int tid  = threadIdx.x;
    const int m    = tid & 15;
    const int q    = (tid >> 4) & 3;
    const int wave = tid >> 6;
    const int r0   = blockIdx.x * 16;
    const int c0   = wave * 32;

    const float*  xrow = x + (size_t)(r0 + m) * CH + q * 8;
    const ushort* w0   = wbf + (size_t)(c0 + m) * CH + q * 8;
    const ushort* w1   = w0 + 16 * CH;

    f32x4 acc0 = {0.f, 0.f, 0.f, 0.f};
    f32x4 acc1 = {0.f, 0.f, 0.f, 0.f};

#pragma unroll
    for (int kc = 0; kc < CH; kc += 32) {
        float4 xa = *(const float4*)(xrow + kc);
        float4 xb = *(const float4*)(xrow + kc + 4);
        bf16x8 a;
        a[0] = (short)f2bf(xa.x); a[1] = (short)f2bf(xa.y);
        a[2] = (short)f2bf(xa.z); a[3] = (short)f2bf(xa.w);
        a[4] = (short)f2bf(xb.x); a[5] = (short)f2bf(xb.y);
        a[6] = (short)f2bf(xb.z); a[7] = (short)f2bf(xb.w);
        bf16x8 b0 = *(const bf16x8*)(w0 + kc);
        bf16x8 b1 = *(const bf16x8*)(w1 + kc);
        acc0 = __builtin_amdgcn_mfma_f32_16x16x32_bf16(a, b0, acc0, 0, 0, 0);
        acc1 = __builtin_amdgcn_mfma_f32_16x16x32_bf16(a, b1, acc1, 0, 0, 0);
    }

    const int col0 = c0 + m;
    const float bb0 = bias[col0];
    const float bb1 = bias[col0 + 16];
#pragma unroll
    for (int r = 0; r < 4; r++) {
        size_t row = (size_t)(r0 + q * 4 + r) * CH;
        h[row + col0]      = f2bf(acc0[r] + bb0);
        h[row + col0 + 16] = f2bf(acc1[r] + bb1);
    }
}

// ---------------- pass 1a: per-block bucket histogram (+ fused W convert) ----------------
__global__ __launch_bounds__(256) void p1_count(const int* __restrict__ ei,
                                                int* __restrict__ counts,
                                                const float* __restrict__ W,
                                                ushort* __restrict__ wbf) {
    __shared__ int cnt[NB];
    const int t = threadIdx.x, k = blockIdx.x;
    if (k >= PBLK) {                 // 64 extra blocks: convert W to bf16
        int i = (k - PBLK) * 256 + t;
        wbf[i] = f2bf(W[i]);
        return;
    }
    for (int j = t; j < NB; j += 256) cnt[j] = 0;
    __syncthreads();
    const int* dp = ei + k * EPB;
    for (int i = t; i < EPB; i += 256) atomicAdd(&cnt[dp[i] >> 7], 1);
    __syncthreads();
    for (int j = t; j < NB; j += 256) counts[j * PBLK + k] = cnt[j];  // bucket-major
}

// ---------------- hierarchical scan, level A: per-bucket row scan ----------------
// Block b: exclusive scan of counts[b][0..256) in place; total -> btot[b].
__global__ __launch_bounds__(256) void scanA(int* __restrict__ counts,
                                             int* __restrict__ btot) {
    __shared__ int s[256];
    const int b = blockIdx.x, t = threadIdx.x;
    int v = counts[b * PBLK + t];
    s[t] = v;
    __syncthreads();
    for (int o = 1; o < 256; o <<= 1) {
        int u = (t >= o) ? s[t - o] : 0;
        __syncthreads();
        s[t] += u;
        __syncthreads();
    }
    counts[b * PBLK + t] = s[t] - v;     // exclusive within bucket
    if (t == 255) btot[b] = s[t];
}

// ---------------- hierarchical scan, level B: bucket bases ----------------
__global__ __launch_bounds__(1024) void scanB(const int* __restrict__ btot,
                                              int* __restrict__ base) {
    __shared__ int s[1024];
    const int t = threadIdx.x;
    int v = (t < NB) ? btot[t] : 0;
    s[t] = v;
    __syncthreads();
    for (int o = 1; o < 1024; o <<= 1) {
        int u = (t >= o) ? s[t - o] : 0;
        __syncthreads();
        s[t] += u;
        __syncthreads();
    }
    if (t <= NB) base[t] = s[t] - v;     // base[NB] = total = E
}

// ---------------- pass 1b: scatter (dst,src) into private slots, SoA ----------------
__global__ __launch_bounds__(256) void p1_write(const int* __restrict__ ei,
                                                const int* __restrict__ counts,
                                                const int* __restrict__ base,
                                                int* __restrict__ dsts,
                                                int* __restrict__ srcs) {
    __shared__ int cur[NB];
    const int t = threadIdx.x, k = blockIdx.x;
    for (int j = t; j < NB; j += 256) cur[j] = base[j] + counts[j * PBLK + k];
    __syncthreads();
    const int* dp = ei + k * EPB;
    const int* sp = ei + E + k * EPB;
    for (int i = t; i < EPB; i += 256) {
        int d = dp[i], s = sp[i];
        int p = atomicAdd(&cur[d >> 7], 1);
        dsts[p] = d;
        srcs[p] = s;
    }
}

// ---------------- pass 2: per-bucket local CSR build ----------------
__global__ __launch_bounds__(256) void p2_build(const int* __restrict__ dsts,
                                                const int* __restrict__ srcs,
                                                const int* __restrict__ base,
                                                int* __restrict__ deg,
                                                int* __restrict__ offs,
                                                int* __restrict__ csr) {
    __shared__ int hist[BSZ], scn[BSZ], cur[BSZ];
    const int b = blockIdx.x, t = threadIdx.x;
    const int lo = base[b], cnt = base[b + 1] - lo;
    if (t < BSZ) hist[t] = 0;
    __syncthreads();
    for (int i = t; i < cnt; i += 256) atomicAdd(&hist[dsts[lo + i] & (BSZ - 1)], 1);
    __syncthreads();
    if (t < BSZ) scn[t] = hist[t];
    __syncthreads();
    for (int o = 1; o < BSZ; o <<= 1) {
        int v = 0;
        if (t < BSZ && t >= o) v = scn[t - o];
        __syncthreads();
        if (t < BSZ) scn[t] += v;
        __syncthreads();
    }
    if (t < BSZ) {
        int excl = scn[t] - hist[t];
        cur[t] = excl;
        int n = b * BSZ + t;
        if (n < N) { deg[n] = hist[t]; offs[n] = lo + excl; }
    }
    __syncthreads();
    for (int i = t; i < cnt; i += 256) {
        int d = dsts[lo + i], s = srcs[lo + i];
        int p = atomicAdd(&cur[d & (BSZ - 1)], 1);
        csr[lo + p] = s;
    }
}

// ---------------- pull aggregation, high-MLP ----------------
// 4 waves/block, one node per wave. Half-waves process different edges;
// lane reads 8 B (4 bf16) -> one 256 B row per half-wave. Unroll x4 =>
// 8 rows in flight per wave. Cross-half shfl_xor reduce, float4 store.
__global__ __launch_bounds__(256) void agg_bf16(const ushort* __restrict__ h,
                                                const int* __restrict__ offs,
                                                const int* __restrict__ deg,
                                                const int* __restrict__ csr,
                                                float* __restrict__ out) {
    const int lane = threadIdx.x & 63;
    const int half = lane >> 5;          // 0/1
    const int cl   = lane & 31;          // channel quad 0..31
    const int n    = blockIdx.x * 4 + (threadIdx.x >> 6);
    const int st   = offs[n];
    const int cnt  = deg[n];
    const ushort* hp = h + (size_t)cl * 4;

    float a0 = 0.f, a1 = 0.f, a2 = 0.f, a3 = 0.f;
    int i = 0;
    for (; i + 8 <= cnt; i += 8) {
        const int e0 = st + i + half;
        int s0 = csr[e0];
        int s1 = csr[e0 + 2];
        int s2 = csr[e0 + 4];
        int s3 = csr[e0 + 6];
        uint2 v0 = *(const uint2*)(hp + (size_t)s0 * CH);
        uint2 v1 = *(const uint2*)(hp + (size_t)s1 * CH);
        uint2 v2 = *(const uint2*)(hp + (size_t)s2 * CH);
        uint2 v3 = *(const uint2*)(hp + (size_t)s3 * CH);
        a0 += bf_lo(v0.x); a1 += bf_hi(v0.x); a2 += bf_lo(v0.y); a3 += bf_hi(v0.y);
        a0 += bf_lo(v1.x); a1 += bf_hi(v1.x); a2 += bf_lo(v1.y); a3 += bf_hi(v1.y);
        a0 += bf_lo(v2.x); a1 += bf_hi(v2.x); a2 += bf_lo(v2.y); a3 += bf_hi(v2.y);
        a0 += bf_lo(v3.x); a1 += bf_hi(v3.x); a2 += bf_lo(v3.y); a3 += bf_hi(v3.y);
    }
    for (; i + 2 <= cnt; i += 2) {
        int s = csr[st + i + half];
        uint2 v = *(const uint2*)(hp + (size_t)s * CH);
        a0 += bf_lo(v.x); a1 += bf_hi(v.x); a2 += bf_lo(v.y); a3 += bf_hi(v.y);
    }
    if (i + half < cnt) {                // odd tail: half 0 only
        int s = csr[st + i + half];
        uint2 v = *(const uint2*)(hp + (size_t)s * CH);
        a0 += bf_lo(v.x); a1 += bf_hi(v.x); a2 += bf_lo(v.y); a3 += bf_hi(v.y);
    }
    a0 += __shfl_xor(a0, 32);
    a1 += __shfl_xor(a1, 32);
    a2 += __shfl_xor(a2, 32);
    a3 += __shfl_xor(a3, 32);
    if (half == 0) {
        float4 r = make_float4(a0, a1, a2, a3);
        *(float4*)(out + (size_t)n * CH + cl * 4) = r;
    }
}

// ---------------- fallback: direct atomic scatter ----------------
__global__ void atomic_agg(const ushort* __restrict__ h, const int* __restrict__ ei,
                           float* __restrict__ out) {
    int tid = blockIdx.x * blockDim.x + threadIdx.x;
    int e  = tid >> 5;
    int cg = (tid & 31) * 4;
    if (e < E) {
        int d = ei[e];
        int s = ei[E + e];
        ushort4 v = *(const ushort4*)(h + (size_t)s * CH + cg);
        float* o = out + (size_t)d * CH + cg;
        atomicAdd(o + 0, __uint_as_float((unsigned)v.x << 16));
        atomicAdd(o + 1, __uint_as_float((unsigned)v.y << 16));
        atomicAdd(o + 2, __uint_as_float((unsigned)v.z << 16));
        atomicAdd(o + 3, __uint_as_float((unsigned)v.w << 16));
    }
}

extern "C" void kernel_launch(void* const* d_in, const int* in_sizes, int n_in,
                              void* d_out, int out_size, void* d_ws, size_t ws_size,
                              hipStream_t stream) {
    const float* x  = (const float*)d_in[0];
    const int*   ei = (const int*)d_in[1];   // [2][E] int32: row0=dst, row1=src
    const float* W  = (const float*)d_in[2];
    const float* b  = (const float*)d_in[3];
    float* out = (float*)d_out;

    char* ws = (char*)d_ws;
    ushort* h   = (ushort*)(ws + H_OFF);
    ushort* wbf = (ushort*)(ws + WBF_OFF);

    if (ws_size >= REQUIRED) {
        int* dsts   = (int*)(ws + DSTS_OFF);
        int* srcs   = (int*)(ws + SRCS_OFF);
        int* csr    = (int*)(ws + CSR_OFF);
        int* counts = (int*)(ws + CNT_OFF);
        int* deg    = (int*)(ws + DEG_OFF);
        int* offs   = (int*)(ws + OFFS_OFF);
        int* base   = (int*)(ws + BASE_OFF);
        int* btot   = (int*)(ws + BTOT_OFF);

        p1_count<<<PBLK + 64, 256, 0, stream>>>(ei, counts, W, wbf);  // + W convert
        gemm_mfma<<<N / 16, 256, 0, stream>>>(x, wbf, b, h);
        scanA<<<NB, 256, 0, stream>>>(counts, btot);
        scanB<<<1, 1024, 0, stream>>>(btot, base);
        p1_write<<<PBLK, 256, 0, stream>>>(ei, counts, base, dsts, srcs);
        p2_build<<<NB, 256, 0, stream>>>(dsts, srcs, base, deg, offs, csr);
        agg_bf16<<<N / 4, 256, 0, stream>>>(h, offs, deg, csr, out);
    } else if (ws_size >= FB_REQUIRED) {
        convert_w<<<64, 256, 0, stream>>>(W, wbf);
        gemm_mfma<<<N / 16, 256, 0, stream>>>(x, wbf, b, h);
        hipMemsetAsync(out, 0, (size_t)out_size * sizeof(float), stream);
        int total = E * 32;
        atomic_agg<<<(total + 255) / 256, 256, 0, stream>>>(h, ei, out);
    }
}